// Round 6
// baseline (398.980 us; speedup 1.0000x reference)
//
#include <hip/hip_runtime.h>
#include <hip/hip_bf16.h>

typedef float f32x4 __attribute__((ext_vector_type(4)));
typedef short s16x8 __attribute__((ext_vector_type(8)));

#define EPS 1e-5f

__device__ __forceinline__ unsigned short f32_to_bf16_rne(float f) {
    unsigned u = __float_as_uint(f);
    unsigned r = u + 0x7FFFu + ((u >> 16) & 1u);
    return (unsigned short)(r >> 16);
}

// packed 2x bf16 via HW converter (RNE): lo = a, hi = b
__device__ __forceinline__ unsigned cvtpk(float a, float b) {
    unsigned d;
    asm("v_cvt_pk_bf16_f32 %0, %1, %2" : "=v"(d) : "v"(a), "v"(b));
    return d;
}

// max over each 16-lane row group via DPP row rotations (no DS pipe)
__device__ __forceinline__ float dppmax16(float v) {
    float t;
    t = __int_as_float(__builtin_amdgcn_update_dpp(0, __float_as_int(v), 0x128, 0xF, 0xF, true));
    v = fmaxf(v, t);
    t = __int_as_float(__builtin_amdgcn_update_dpp(0, __float_as_int(v), 0x124, 0xF, 0xF, true));
    v = fmaxf(v, t);
    t = __int_as_float(__builtin_amdgcn_update_dpp(0, __float_as_int(v), 0x122, 0xF, 0xF, true));
    v = fmaxf(v, t);
    t = __int_as_float(__builtin_amdgcn_update_dpp(0, __float_as_int(v), 0x121, 0xF, 0xF, true));
    v = fmaxf(v, t);
    return v;
}

// ---------------- weight packing + buffer zeroing ----------------
// 6 matrices, each 64x64 packed as [2][4][64][8] bf16 (4096 ushorts):
//  m=0: W1xi = W1a[0:64]-W1a[64:128]   m=1: W1xj = W1a[64:128]   m=2: W1b
//  m=3: W2xi = W2a[0:64]-W2a[64:128]   m=4: W2xj = W2a[64:128]   m=5: W2b
__global__ void pack_all(const float* __restrict__ W1a, const float* __restrict__ W1b,
                         const float* __restrict__ W2a, const float* __restrict__ W2b,
                         unsigned short* __restrict__ p, float* __restrict__ stats,
                         int* __restrict__ count, int N) {
    int idx = blockIdx.x * 256 + threadIdx.x;
    if (idx < 24576) {
        int m = idx >> 12;
        int t = idx & 4095;
        int j = t & 7;
        int lane = (t >> 3) & 63;
        int mt = (t >> 9) & 3;
        int kc = t >> 11;
        int k = kc * 32 + (lane >> 4) * 8 + j;
        int c = mt * 16 + (lane & 15);
        float v;
        switch (m) {
            case 0: v = W1a[k * 64 + c] - W1a[(k + 64) * 64 + c]; break;
            case 1: v = W1a[(k + 64) * 64 + c]; break;
            case 2: v = W1b[k * 64 + c]; break;
            case 3: v = W2a[k * 64 + c] - W2a[(k + 64) * 64 + c]; break;
            case 4: v = W2a[(k + 64) * 64 + c]; break;
            default: v = W2b[k * 64 + c]; break;
        }
        p[idx] = f32_to_bf16_rne(v);
    } else if (idx < 24832) {
        stats[idx - 24576] = 0.f;
    } else if (idx - 24832 < N) {
        count[idx - 24832] = 0;
    }
}

// ---------------- f32 -> bf16 table convert + dst histogram ----------------
__global__ void cvt_hist(const float* __restrict__ in, unsigned short* __restrict__ out, int n4,
                         const int* __restrict__ edst, int* __restrict__ count, int E) {
    int i = blockIdx.x * 256 + threadIdx.x;
    if (i < n4) {
        f32x4 v = ((const f32x4*)in)[i];
        uint2 pr;
        pr.x = cvtpk(v[0], v[1]);
        pr.y = cvtpk(v[2], v[3]);
        *(uint2*)(out + i * 4) = pr;
    }
    if (i < E) atomicAdd(&count[edst[i]], 1);
}

// ---------------- two-level scan: 1024 elems/block ----------------
__global__ void scan1(const int* __restrict__ count, int* __restrict__ offsets,
                      int* __restrict__ bsums, int N) {
    __shared__ int sdata[256];
    int t = threadIdx.x;
    int base = blockIdx.x * 1024 + t * 4;
    int4 v = {0, 0, 0, 0};
    if (base + 3 < N) {
        v = *(const int4*)(count + base);
    } else {
        if (base + 0 < N) v.x = count[base + 0];
        if (base + 1 < N) v.y = count[base + 1];
        if (base + 2 < N) v.z = count[base + 2];
    }
    int s = v.x + v.y + v.z + v.w;
    sdata[t] = s;
    __syncthreads();
    for (int off = 1; off < 256; off <<= 1) {
        int u = (t >= off) ? sdata[t - off] : 0;
        __syncthreads();
        sdata[t] += u;
        __syncthreads();
    }
    int excl = sdata[t] - s;
    if (t == 255) bsums[blockIdx.x] = sdata[255];
    int o0 = excl;
    int o1 = o0 + v.x;
    int o2 = o1 + v.y;
    int o3 = o2 + v.z;
    if (base + 0 < N) offsets[base + 0] = o0;
    if (base + 1 < N) offsets[base + 1] = o1;
    if (base + 2 < N) offsets[base + 2] = o2;
    if (base + 3 < N) offsets[base + 3] = o3;
}

__global__ void scan2(int* __restrict__ bsums, int* __restrict__ offsets, int N, int nb) {
    __shared__ int sdata[256];
    int t = threadIdx.x;
    int s = (t < nb) ? bsums[t] : 0;
    sdata[t] = s;
    __syncthreads();
    for (int off = 1; off < 256; off <<= 1) {
        int u = (t >= off) ? sdata[t - off] : 0;
        __syncthreads();
        sdata[t] += u;
        __syncthreads();
    }
    if (t < nb) bsums[t] = sdata[t] - s;
    if (t == 255) offsets[N] = sdata[255];
}

__global__ void scan3(int* __restrict__ offsets, int* __restrict__ cursor,
                      const int* __restrict__ bsums, int N) {
    int i = blockIdx.x * 256 + threadIdx.x;
    if (i < N) {
        int v = offsets[i] + bsums[i >> 10];
        offsets[i] = v;
        cursor[i] = v;
    }
}

__global__ void scatter_kernel(const int* __restrict__ esrc, const int* __restrict__ edst,
                               int* __restrict__ cursor, int* __restrict__ ssrc, int E) {
    int i = blockIdx.x * 256 + threadIdx.x;
    if (i < E) {
        int d = edst[i];
        int pos = atomicAdd(&cursor[d], 1);
        ssrc[pos] = esrc[i];
    }
}

// ---------------- fused EdgeConv on dst-sorted edges, 3-stage pipelined ----------------
// h = relu(xi@Wxi + xj@Wxj + b); C-init = bias + xi-part (once per node).
// Each wave owns 2 consecutive nodes. Tile stream across both nodes is software-
// pipelined: ssrc(i+2) / row-gather(i+1) / compute(i).
#define LSTR 88  // LDS row stride in ushorts (44 dwords: near-conflict-free, 16B aligned)
__global__ __launch_bounds__(256, 3) void edgeconv_sorted(
    const unsigned short* __restrict__ xb,    // [N][64] bf16 features
    const int* __restrict__ ssrc,             // [E] src idx sorted by dst
    const int* __restrict__ offsets,          // [N+1]
    const unsigned short* __restrict__ pWxi,  // packed [2][4][64][8]
    const unsigned short* __restrict__ pWxj,
    const unsigned short* __restrict__ pWb,
    const float* __restrict__ ba,
    const float* __restrict__ bb,
    float* __restrict__ out,                  // [N][64] f32 (fully written)
    int N) {
    __shared__ __align__(16) unsigned short xstage[4][16 * LSTR];
    __shared__ __align__(16) unsigned short h1lds[4][16 * LSTR];
    const int tid = threadIdx.x;
    const int w = tid >> 6;
    const int lane = tid & 63;
    const int g = lane >> 4;
    const int r = lane & 15;
    const int srow = lane >> 2;  // staging row slot
    const int schk = lane & 3;   // staging 16B chunk

    const int gw = blockIdx.x * 4 + w;
    const int nA = gw * 2;
    if (nA >= N) return;
    const int nB = nA + 1;

    unsigned short* myx = xstage[w];
    unsigned short* myl = h1lds[w];

    const int oA = offsets[nA];
    const int oAB = offsets[nA + 1];
    const int oB2 = (nB < N) ? offsets[nB + 1] : oAB;

    // pipeline positions (t<0 = none)
    int t0 = -1, e0 = 0, t1 = -1, e1 = 0, t2 = -1, e2 = 0;
    if (oA < oAB) { t0 = oA; e0 = oAB; }
    else if (oAB < oB2) { t0 = oAB; e0 = oB2; }
    auto nxt = [&](int t, int e, int& tn, int& en) {
        tn = -1; en = 0;
        if (t < 0) return;
        int tt = t + 16;
        if (tt < e) { tn = tt; en = e; }
        else if (e == oAB && oAB < oB2) { tn = oAB; en = oB2; }
    };
    nxt(t0, e0, t1, e1);
    nxt(t1, e1, t2, e2);

    // stage-0/1 prefetch: ssrc for t0 and t1
    int sv0 = 0, sv1 = 0;
    if (t0 >= 0) sv0 = ssrc[min(t0 + srow, e0 - 1)];
    if (t1 >= 0) sv1 = ssrc[min(t1 + srow, e1 - 1)];

    // xi rows for both nodes (contiguous; B clamped)
    s16x8 xiA1 = *(const s16x8*)(xb + nA * 64 + g * 8);
    s16x8 xiA2 = *(const s16x8*)(xb + nA * 64 + 32 + g * 8);
    const int rowB = min(nB, N - 1);
    s16x8 xiB1 = *(const s16x8*)(xb + rowB * 64 + g * 8);
    s16x8 xiB2 = *(const s16x8*)(xb + rowB * 64 + 32 + g * 8);

    // first tile's rows
    s16x8 ra = {}, rb = {};
    if (t0 >= 0) {
        ra = *(const s16x8*)(xb + sv0 * 64 + schk * 8);
        rb = *(const s16x8*)(xb + sv0 * 64 + 32 + schk * 8);
    }

    // persistent weight fragments
    s16x8 axj[2][4], ab[2][4];
#pragma unroll
    for (int kc = 0; kc < 2; ++kc)
#pragma unroll
        for (int mt = 0; mt < 4; ++mt) {
            axj[kc][mt] = *(const s16x8*)(pWxj + ((kc * 4 + mt) * 64 + lane) * 8);
            ab[kc][mt] = *(const s16x8*)(pWb + ((kc * 4 + mt) * 64 + lane) * 8);
        }

    f32x4 rm[4];
    const f32x4 zf = {0.f, 0.f, 0.f, 0.f};

    auto build_accxi = [&](s16x8 x1, s16x8 x2, f32x4* accxi) {
#pragma unroll
        for (int mt = 0; mt < 4; ++mt) {
            f32x4 c = *(const f32x4*)(ba + mt * 16 + g * 4);
            s16x8 f0 = *(const s16x8*)(pWxi + ((0 * 4 + mt) * 64 + lane) * 8);
            c = __builtin_amdgcn_mfma_f32_16x16x32_bf16(f0, x1, c, 0, 0, 0);
            s16x8 f1 = *(const s16x8*)(pWxi + ((1 * 4 + mt) * 64 + lane) * 8);
            accxi[mt] = __builtin_amdgcn_mfma_f32_16x16x32_bf16(f1, x2, c, 0, 0, 0);
        }
    };

    auto do_tile = [&](const f32x4* accxi) {
        const int tc = t0, ec = e0;
        // stage current rows to LDS (per-wave, in-order DS => no barrier)
        *(s16x8*)(myx + srow * LSTR + schk * 8) = ra;
        *(s16x8*)(myx + srow * LSTR + 32 + schk * 8) = rb;
        s16x8 xj1 = *(const s16x8*)(myx + r * LSTR + g * 8);
        s16x8 xj2 = *(const s16x8*)(myx + r * LSTR + 32 + g * 8);

        // prefetch: rows for t1 (sv1 resident), ssrc for t2
        if (t1 >= 0) {
            int s = sv1;
            ra = *(const s16x8*)(xb + s * 64 + schk * 8);
            rb = *(const s16x8*)(xb + s * 64 + 32 + schk * 8);
        }
        if (t2 >= 0) sv1 = ssrc[min(t2 + srow, e2 - 1)];
        t0 = t1; e0 = e1;
        t1 = t2; e1 = e2;
        { int tn, en; nxt(t1, e1, tn, en); t2 = tn; e2 = en; }

        // layer 1 (C-init = xi-part + bias)
        f32x4 acc[4];
#pragma unroll
        for (int mt = 0; mt < 4; ++mt) {
            acc[mt] = __builtin_amdgcn_mfma_f32_16x16x32_bf16(axj[0][mt], xj1, accxi[mt], 0, 0, 0);
            acc[mt] = __builtin_amdgcn_mfma_f32_16x16x32_bf16(axj[1][mt], xj2, acc[mt], 0, 0, 0);
        }
        // relu + pack to bf16 (HW cvt_pk), bounce through LDS
#pragma unroll
        for (int mt = 0; mt < 4; ++mt) {
            uint2 pr;
            pr.x = cvtpk(fmaxf(acc[mt][0], 0.f), fmaxf(acc[mt][1], 0.f));
            pr.y = cvtpk(fmaxf(acc[mt][2], 0.f), fmaxf(acc[mt][3], 0.f));
            *(uint2*)(myl + r * LSTR + mt * 16 + g * 4) = pr;
        }
        s16x8 p0 = *(const s16x8*)(myl + r * LSTR + g * 8);
        s16x8 p1 = *(const s16x8*)(myl + r * LSTR + 32 + g * 8);

        f32x4 acc2[4];
#pragma unroll
        for (int mt = 0; mt < 4; ++mt) {
            acc2[mt] = __builtin_amdgcn_mfma_f32_16x16x32_bf16(ab[0][mt], p0, zf, 0, 0, 0);
            acc2[mt] = __builtin_amdgcn_mfma_f32_16x16x32_bf16(ab[1][mt], p1, acc2[mt], 0, 0, 0);
        }
        if (tc + r < ec) {
#pragma unroll
            for (int mt = 0; mt < 4; ++mt)
#pragma unroll
                for (int q = 0; q < 4; ++q)
                    rm[mt][q] = fmaxf(rm[mt][q], acc2[mt][q]);
        }
    };

    auto finish = [&](int node) {
#pragma unroll
        for (int mt = 0; mt < 4; ++mt)
#pragma unroll
            for (int q = 0; q < 4; ++q)
                rm[mt][q] = dppmax16(rm[mt][q]);
        if (r == 0) {
#pragma unroll
            for (int mt = 0; mt < 4; ++mt) {
                f32x4 b2 = *(const f32x4*)(bb + mt * 16 + g * 4);
                f32x4 o;
#pragma unroll
                for (int q = 0; q < 4; ++q) o[q] = fmaxf(rm[mt][q] + b2[q], 0.f);
                *(f32x4*)(out + node * 64 + mt * 16 + g * 4) = o;
            }
        }
    };

    // ---- node A ----
    f32x4 accxiA[4];
    build_accxi(xiA1, xiA2, accxiA);
#pragma unroll
    for (int mt = 0; mt < 4; ++mt) rm[mt] = (f32x4){-INFINITY, -INFINITY, -INFINITY, -INFINITY};
    while (t0 >= 0 && e0 == oAB) do_tile(accxiA);

    // node B accxi (MFMA) before A's butterfly for overlap
    f32x4 accxiB[4];
    build_accxi(xiB1, xiB2, accxiB);

    finish(nA);

    // ---- node B ----
#pragma unroll
    for (int mt = 0; mt < 4; ++mt) rm[mt] = (f32x4){-INFINITY, -INFINITY, -INFINITY, -INFINITY};
    while (t0 >= 0) do_tile(accxiB);
    if (nB < N) finish(nB);
}

// ---------------- batchnorm stats: per-channel sum & sumsq ----------------
__global__ void bn_stats(const float* __restrict__ in, float* __restrict__ stats, int N) {
    __shared__ float ls[4][64];
    __shared__ float lss[4][64];
    int c = threadIdx.x & 63;
    int rg = threadIdx.x >> 6;
    float s = 0.f, ss = 0.f;
    for (int row = blockIdx.x * 4 + rg; row < N; row += gridDim.x * 4) {
        float v = in[row * 64 + c];
        s += v;
        ss += v * v;
    }
    ls[rg][c] = s;
    lss[rg][c] = ss;
    __syncthreads();
    if (rg == 0) {
        s = ls[0][c] + ls[1][c] + ls[2][c] + ls[3][c];
        ss = lss[0][c] + lss[1][c] + lss[2][c] + lss[3][c];
        atomicAdd(&stats[c], s);
        atomicAdd(&stats[64 + c], ss);
    }
}

// ---------------- batchnorm apply (optionally emit bf16 table for next layer) ----------------
__global__ void bn_apply(const float* __restrict__ in, const float* __restrict__ stats,
                         const float* __restrict__ gamma, const float* __restrict__ beta,
                         unsigned short* __restrict__ outb, float* __restrict__ outf,
                         int n4, float invN) {
    int i = blockIdx.x * 256 + threadIdx.x;
    if (i >= n4) return;
    int c0 = (i * 4) & 63;
    f32x4 v = ((const f32x4*)in)[i];
    f32x4 o;
#pragma unroll
    for (int q = 0; q < 4; ++q) {
        int c = c0 + q;
        float mean = stats[c] * invN;
        float var = stats[64 + c] * invN - mean * mean;
        float sc = gamma[c] * rsqrtf(var + EPS);
        o[q] = (v[q] - mean) * sc + beta[c];
    }
    if (outb) {
        uint2 pr;
        pr.x = cvtpk(o[0], o[1]);
        pr.y = cvtpk(o[2], o[3]);
        *(uint2*)(outb + i * 4) = pr;
    } else {
        ((f32x4*)outf)[i] = o;
    }
}

extern "C" void kernel_launch(void* const* d_in, const int* in_sizes, int n_in,
                              void* d_out, int out_size, void* d_ws, size_t ws_size,
                              hipStream_t stream) {
    const float* x = (const float*)d_in[0];
    const int* ei = (const int*)d_in[1];
    // d_in[2] = batch (unused, single graph)
    const float* W1a = (const float*)d_in[3];
    const float* b1a = (const float*)d_in[4];
    const float* W1b = (const float*)d_in[5];
    const float* b1b = (const float*)d_in[6];
    const float* gamma1 = (const float*)d_in[7];
    const float* beta1 = (const float*)d_in[8];
    const float* W2a = (const float*)d_in[9];
    const float* b2a = (const float*)d_in[10];
    const float* W2b = (const float*)d_in[11];
    const float* b2b = (const float*)d_in[12];
    const float* gamma2 = (const float*)d_in[13];
    const float* beta2 = (const float*)d_in[14];

    const int N = in_sizes[0] / 64;
    const int E = in_sizes[1] / 2;
    const int NC = N * 64;

    char* ws = (char*)d_ws;
    size_t off = 0;
    auto alloc = [&](size_t bytes) {
        char* p = ws + off;
        off += (bytes + 255) & ~(size_t)255;
        return p;
    };
    float* acc = (float*)alloc((size_t)NC * 4);                   // layer-1 pre-BN output
    unsigned short* xb = (unsigned short*)alloc((size_t)NC * 2);  // bf16 feature table
    unsigned short* pw = (unsigned short*)alloc(24576 * 2);
    float* stats = (float*)alloc(256 * 4);
    int* count = (int*)alloc((size_t)N * 4);
    int* offsets = (int*)alloc((size_t)(N + 1) * 4);
    int* cursor = (int*)alloc((size_t)(N + 1) * 4);
    int* ssrc = (int*)alloc((size_t)E * 4);
    int* bsums = (int*)alloc(1024 * 4);

    const int* esrc = ei;
    const int* edst = ei + E;

    // pack weights + zero stats/count
    int pgrid = (24832 + N + 255) / 256;
    pack_all<<<pgrid, 256, 0, stream>>>(W1a, W1b, W2a, W2b, pw, stats, count, N);

    // bf16 table + dst histogram
    int n4 = NC / 4;
    int big = max(n4, E);
    cvt_hist<<<(big + 255) / 256, 256, 0, stream>>>(x, xb, n4, edst, count, E);

    // two-level scan (counting sort offsets)
    int nb = (N + 1023) / 1024;
    scan1<<<nb, 256, 0, stream>>>(count, offsets, bsums, N);
    scan2<<<1, 256, 0, stream>>>(bsums, offsets, N, nb);
    scan3<<<(N + 255) / 256, 256, 0, stream>>>(offsets, cursor, bsums, N);
    scatter_kernel<<<(E + 255) / 256, 256, 0, stream>>>(esrc, edst, cursor, ssrc, E);

    int cgrid = (n4 + 255) / 256;
    int egrid = (N + 7) / 8;  // 4 waves/block, 2 nodes/wave

    // layer 1
    edgeconv_sorted<<<egrid, 256, 0, stream>>>(xb, ssrc, offsets, pw, pw + 4096, pw + 8192,
                                               b1a, b1b, acc, N);
    bn_stats<<<512, 256, 0, stream>>>(acc, stats, N);
    bn_apply<<<cgrid, 256, 0, stream>>>(acc, stats, gamma1, beta1, xb, nullptr, n4, 1.0f / N);

    // layer 2
    edgeconv_sorted<<<egrid, 256, 0, stream>>>(xb, ssrc, offsets, pw + 12288, pw + 16384,
                                               pw + 20480, b2a, b2b, (float*)d_out, N);
    bn_stats<<<512, 256, 0, stream>>>((float*)d_out, stats + 128, N);
    bn_apply<<<cgrid, 256, 0, stream>>>((float*)d_out, stats + 128, gamma2, beta2, nullptr,
                                        (float*)d_out, n4, 1.0f / N);
}

// Round 7
// 297.089 us; speedup vs baseline: 1.3430x; 1.3430x over previous
//
#include <hip/hip_runtime.h>
#include <hip/hip_bf16.h>

typedef float f32x4 __attribute__((ext_vector_type(4)));
typedef short s16x8 __attribute__((ext_vector_type(8)));

#define EPS 1e-5f

__device__ __forceinline__ unsigned short f32_to_bf16_rne(float f) {
    unsigned u = __float_as_uint(f);
    unsigned r = u + 0x7FFFu + ((u >> 16) & 1u);
    return (unsigned short)(r >> 16);
}

// packed 2x bf16 via HW converter (RNE): lo = a, hi = b
__device__ __forceinline__ unsigned cvtpk(float a, float b) {
    unsigned d;
    asm("v_cvt_pk_bf16_f32 %0, %1, %2" : "=v"(d) : "v"(a), "v"(b));
    return d;
}

// max over each 16-lane row group via DPP row rotations (VALU, no DS pipe)
__device__ __forceinline__ float dppmax16(float v) {
    float t;
    t = __int_as_float(__builtin_amdgcn_update_dpp(0, __float_as_int(v), 0x128, 0xF, 0xF, true));
    v = fmaxf(v, t);
    t = __int_as_float(__builtin_amdgcn_update_dpp(0, __float_as_int(v), 0x124, 0xF, 0xF, true));
    v = fmaxf(v, t);
    t = __int_as_float(__builtin_amdgcn_update_dpp(0, __float_as_int(v), 0x122, 0xF, 0xF, true));
    v = fmaxf(v, t);
    t = __int_as_float(__builtin_amdgcn_update_dpp(0, __float_as_int(v), 0x121, 0xF, 0xF, true));
    v = fmaxf(v, t);
    return v;
}

// ---------------- weight packing + buffer zeroing ----------------
// 6 matrices, each 64x64 packed as [2][4][64][8] bf16 (4096 ushorts):
//  m=0: W1xi = W1a[0:64]-W1a[64:128]   m=1: W1xj = W1a[64:128]   m=2: W1b
//  m=3: W2xi = W2a[0:64]-W2a[64:128]   m=4: W2xj = W2a[64:128]   m=5: W2b
__global__ void pack_all(const float* __restrict__ W1a, const float* __restrict__ W1b,
                         const float* __restrict__ W2a, const float* __restrict__ W2b,
                         unsigned short* __restrict__ p, float* __restrict__ stats,
                         int* __restrict__ count, int N) {
    int idx = blockIdx.x * 256 + threadIdx.x;
    if (idx < 24576) {
        int m = idx >> 12;
        int t = idx & 4095;
        int j = t & 7;
        int lane = (t >> 3) & 63;
        int mt = (t >> 9) & 3;
        int kc = t >> 11;
        int k = kc * 32 + (lane >> 4) * 8 + j;
        int c = mt * 16 + (lane & 15);
        float v;
        switch (m) {
            case 0: v = W1a[k * 64 + c] - W1a[(k + 64) * 64 + c]; break;
            case 1: v = W1a[(k + 64) * 64 + c]; break;
            case 2: v = W1b[k * 64 + c]; break;
            case 3: v = W2a[k * 64 + c] - W2a[(k + 64) * 64 + c]; break;
            case 4: v = W2a[(k + 64) * 64 + c]; break;
            default: v = W2b[k * 64 + c]; break;
        }
        p[idx] = f32_to_bf16_rne(v);
    } else if (idx < 24832) {
        stats[idx - 24576] = 0.f;
    } else if (idx - 24832 < N) {
        count[idx - 24832] = 0;
    }
}

// ---------------- f32 -> bf16 table convert + dst histogram ----------------
__global__ void cvt_hist(const float* __restrict__ in, unsigned short* __restrict__ out, int n4,
                         const int* __restrict__ edst, int* __restrict__ count, int E) {
    int i = blockIdx.x * 256 + threadIdx.x;
    if (i < n4) {
        f32x4 v = ((const f32x4*)in)[i];
        uint2 pr;
        pr.x = cvtpk(v[0], v[1]);
        pr.y = cvtpk(v[2], v[3]);
        *(uint2*)(out + i * 4) = pr;
    }
    if (i < E) atomicAdd(&count[edst[i]], 1);
}

// ---------------- two-level scan: 1024 elems/block ----------------
__global__ void scan1(const int* __restrict__ count, int* __restrict__ offsets,
                      int* __restrict__ bsums, int N) {
    __shared__ int sdata[256];
    int t = threadIdx.x;
    int base = blockIdx.x * 1024 + t * 4;
    int4 v = {0, 0, 0, 0};
    if (base + 3 < N) {
        v = *(const int4*)(count + base);
    } else {
        if (base + 0 < N) v.x = count[base + 0];
        if (base + 1 < N) v.y = count[base + 1];
        if (base + 2 < N) v.z = count[base + 2];
    }
    int s = v.x + v.y + v.z + v.w;
    sdata[t] = s;
    __syncthreads();
    for (int off = 1; off < 256; off <<= 1) {
        int u = (t >= off) ? sdata[t - off] : 0;
        __syncthreads();
        sdata[t] += u;
        __syncthreads();
    }
    int excl = sdata[t] - s;
    if (t == 255) bsums[blockIdx.x] = sdata[255];
    int o0 = excl;
    int o1 = o0 + v.x;
    int o2 = o1 + v.y;
    int o3 = o2 + v.z;
    if (base + 0 < N) offsets[base + 0] = o0;
    if (base + 1 < N) offsets[base + 1] = o1;
    if (base + 2 < N) offsets[base + 2] = o2;
    if (base + 3 < N) offsets[base + 3] = o3;
}

__global__ void scan2(int* __restrict__ bsums, int* __restrict__ offsets, int N, int nb) {
    __shared__ int sdata[256];
    int t = threadIdx.x;
    int s = (t < nb) ? bsums[t] : 0;
    sdata[t] = s;
    __syncthreads();
    for (int off = 1; off < 256; off <<= 1) {
        int u = (t >= off) ? sdata[t - off] : 0;
        __syncthreads();
        sdata[t] += u;
        __syncthreads();
    }
    if (t < nb) bsums[t] = sdata[t] - s;
    if (t == 255) offsets[N] = sdata[255];
}

__global__ void scan3(int* __restrict__ offsets, int* __restrict__ cursor,
                      const int* __restrict__ bsums, int N) {
    int i = blockIdx.x * 256 + threadIdx.x;
    if (i < N) {
        int v = offsets[i] + bsums[i >> 10];
        offsets[i] = v;
        cursor[i] = v;
    }
}

__global__ void scatter_kernel(const int* __restrict__ esrc, const int* __restrict__ edst,
                               int* __restrict__ cursor, int* __restrict__ ssrc, int E) {
    int i = blockIdx.x * 256 + threadIdx.x;
    if (i < E) {
        int d = edst[i];
        int pos = atomicAdd(&cursor[d], 1);
        ssrc[pos] = esrc[i];
    }
}

// ---------------- fused EdgeConv on dst-sorted edges ----------------
// h = relu(xi@Wxi + xj@Wxj + b); C-init = bias + xi-part (once per node).
// R5 skeleton (no address-taken locals -> no scratch) + static 1-deep tile
// prefetch: next tile's ssrc+rows land in named registers before this tile's
// MFMA chain issues.
#define LSTR 88  // LDS row stride in ushorts (44 dwords: near-conflict-free, 16B aligned)
__global__ __launch_bounds__(256, 3) void edgeconv_sorted(
    const unsigned short* __restrict__ xb,    // [N][64] bf16 features
    const int* __restrict__ ssrc,             // [E] src idx sorted by dst
    const int* __restrict__ offsets,          // [N+1]
    const unsigned short* __restrict__ pWxi,  // packed [2][4][64][8]
    const unsigned short* __restrict__ pWxj,
    const unsigned short* __restrict__ pWb,
    const float* __restrict__ ba,
    const float* __restrict__ bb,
    float* __restrict__ out,                  // [N][64] f32 (fully written)
    int N) {
    __shared__ __align__(16) unsigned short xstage[4][16 * LSTR];
    __shared__ __align__(16) unsigned short h1lds[4][16 * LSTR];
    const int tid = threadIdx.x;
    const int w = tid >> 6;
    const int lane = tid & 63;
    const int g = lane >> 4;
    const int r = lane & 15;
    const int srow = lane >> 2;  // staging: row slot this lane serves
    const int schk = lane & 3;   // staging: 16B chunk within row half

    // persistent weight fragments: xj-part of layer1 + layer2
    s16x8 axj[2][4], ab[2][4];
#pragma unroll
    for (int kc = 0; kc < 2; ++kc)
#pragma unroll
        for (int mt = 0; mt < 4; ++mt) {
            axj[kc][mt] = *(const s16x8*)(pWxj + ((kc * 4 + mt) * 64 + lane) * 8);
            ab[kc][mt] = *(const s16x8*)(pWb + ((kc * 4 + mt) * 64 + lane) * 8);
        }

    unsigned short* myx = xstage[w];
    unsigned short* myl = h1lds[w];
    const int totalWaves = gridDim.x * 4;
    const f32x4 zf = {0.f, 0.f, 0.f, 0.f};

    for (int node = blockIdx.x * 4 + w; node < N; node += totalWaves) {
        const int segB = offsets[node];
        const int segE = offsets[node + 1];

        f32x4 rm[4];
#pragma unroll
        for (int mt = 0; mt < 4; ++mt)
            rm[mt] = (f32x4){-INFINITY, -INFINITY, -INFINITY, -INFINITY};

        if (segB < segE) {
            // first tile prefetch (ssrc + rows) before accxi MFMA work
            int sv = ssrc[min(segB + srow, segE - 1)];
            s16x8 ra = *(const s16x8*)(xb + sv * 64 + schk * 8);
            s16x8 rb = *(const s16x8*)(xb + sv * 64 + 32 + schk * 8);

            // xi-part + bias, once per node (broadcast across the 16 columns)
            s16x8 xi1 = *(const s16x8*)(xb + node * 64 + g * 8);
            s16x8 xi2 = *(const s16x8*)(xb + node * 64 + 32 + g * 8);
            f32x4 accxi[4];
#pragma unroll
            for (int mt = 0; mt < 4; ++mt)
                accxi[mt] = *(const f32x4*)(ba + mt * 16 + g * 4);
#pragma unroll
            for (int mt = 0; mt < 4; ++mt) {
                s16x8 f0 = *(const s16x8*)(pWxi + ((0 * 4 + mt) * 64 + lane) * 8);
                accxi[mt] = __builtin_amdgcn_mfma_f32_16x16x32_bf16(f0, xi1, accxi[mt], 0, 0, 0);
                s16x8 f1 = *(const s16x8*)(pWxi + ((1 * 4 + mt) * 64 + lane) * 8);
                accxi[mt] = __builtin_amdgcn_mfma_f32_16x16x32_bf16(f1, xi2, accxi[mt], 0, 0, 0);
            }

            for (int t0 = segB; t0 < segE; t0 += 16) {
                // stage prefetched rows (per-wave LDS: in-order, no barrier)
                *(s16x8*)(myx + srow * LSTR + schk * 8) = ra;
                *(s16x8*)(myx + srow * LSTR + 32 + schk * 8) = rb;
                s16x8 xj1 = *(const s16x8*)(myx + r * LSTR + g * 8);
                s16x8 xj2 = *(const s16x8*)(myx + r * LSTR + 32 + g * 8);

                // prefetch next tile before the compute chain
                int t1 = t0 + 16;
                if (t1 < segE) {
                    int sv2 = ssrc[min(t1 + srow, segE - 1)];
                    ra = *(const s16x8*)(xb + sv2 * 64 + schk * 8);
                    rb = *(const s16x8*)(xb + sv2 * 64 + 32 + schk * 8);
                }

                // layer 1 (C-init = xi-part + bias)
                f32x4 acc[4];
#pragma unroll
                for (int mt = 0; mt < 4; ++mt) {
                    acc[mt] = __builtin_amdgcn_mfma_f32_16x16x32_bf16(axj[0][mt], xj1, accxi[mt], 0, 0, 0);
                    acc[mt] = __builtin_amdgcn_mfma_f32_16x16x32_bf16(axj[1][mt], xj2, acc[mt], 0, 0, 0);
                }

                // relu + HW bf16 pack, bounce through LDS
#pragma unroll
                for (int mt = 0; mt < 4; ++mt) {
                    uint2 pr;
                    pr.x = cvtpk(fmaxf(acc[mt][0], 0.f), fmaxf(acc[mt][1], 0.f));
                    pr.y = cvtpk(fmaxf(acc[mt][2], 0.f), fmaxf(acc[mt][3], 0.f));
                    *(uint2*)(myl + r * LSTR + mt * 16 + g * 4) = pr;
                }
                s16x8 p0 = *(const s16x8*)(myl + r * LSTR + g * 8);
                s16x8 p1 = *(const s16x8*)(myl + r * LSTR + 32 + g * 8);

                f32x4 acc2[4];
#pragma unroll
                for (int mt = 0; mt < 4; ++mt) {
                    acc2[mt] = __builtin_amdgcn_mfma_f32_16x16x32_bf16(ab[0][mt], p0, zf, 0, 0, 0);
                    acc2[mt] = __builtin_amdgcn_mfma_f32_16x16x32_bf16(ab[1][mt], p1, acc2[mt], 0, 0, 0);
                }

                if (t0 + r < segE) {
#pragma unroll
                    for (int mt = 0; mt < 4; ++mt)
#pragma unroll
                        for (int q = 0; q < 4; ++q)
                            rm[mt][q] = fmaxf(rm[mt][q], acc2[mt][q]);
                }
            }
        }

        // reduce across the 16 edge-columns (DPP row rotations)
#pragma unroll
        for (int mt = 0; mt < 4; ++mt)
#pragma unroll
            for (int q = 0; q < 4; ++q)
                rm[mt][q] = dppmax16(rm[mt][q]);

        if (r == 0) {
#pragma unroll
            for (int mt = 0; mt < 4; ++mt) {
                f32x4 b2 = *(const f32x4*)(bb + mt * 16 + g * 4);
                f32x4 o;
#pragma unroll
                for (int q = 0; q < 4; ++q) o[q] = fmaxf(rm[mt][q] + b2[q], 0.f);
                *(f32x4*)(out + node * 64 + mt * 16 + g * 4) = o;
            }
        }
    }
}

// ---------------- batchnorm stats: per-channel sum & sumsq ----------------
__global__ void bn_stats(const float* __restrict__ in, float* __restrict__ stats, int N) {
    __shared__ float ls[4][64];
    __shared__ float lss[4][64];
    int c = threadIdx.x & 63;
    int rg = threadIdx.x >> 6;
    float s = 0.f, ss = 0.f;
    for (int row = blockIdx.x * 4 + rg; row < N; row += gridDim.x * 4) {
        float v = in[row * 64 + c];
        s += v;
        ss += v * v;
    }
    ls[rg][c] = s;
    lss[rg][c] = ss;
    __syncthreads();
    if (rg == 0) {
        s = ls[0][c] + ls[1][c] + ls[2][c] + ls[3][c];
        ss = lss[0][c] + lss[1][c] + lss[2][c] + lss[3][c];
        atomicAdd(&stats[c], s);
        atomicAdd(&stats[64 + c], ss);
    }
}

// ---------------- batchnorm apply (optionally emit bf16 table for next layer) ----------------
__global__ void bn_apply(const float* __restrict__ in, const float* __restrict__ stats,
                         const float* __restrict__ gamma, const float* __restrict__ beta,
                         unsigned short* __restrict__ outb, float* __restrict__ outf,
                         int n4, float invN) {
    int i = blockIdx.x * 256 + threadIdx.x;
    if (i >= n4) return;
    int c0 = (i * 4) & 63;
    f32x4 v = ((const f32x4*)in)[i];
    f32x4 o;
#pragma unroll
    for (int q = 0; q < 4; ++q) {
        int c = c0 + q;
        float mean = stats[c] * invN;
        float var = stats[64 + c] * invN - mean * mean;
        float sc = gamma[c] * rsqrtf(var + EPS);
        o[q] = (v[q] - mean) * sc + beta[c];
    }
    if (outb) {
        uint2 pr;
        pr.x = cvtpk(o[0], o[1]);
        pr.y = cvtpk(o[2], o[3]);
        *(uint2*)(outb + i * 4) = pr;
    } else {
        ((f32x4*)outf)[i] = o;
    }
}

extern "C" void kernel_launch(void* const* d_in, const int* in_sizes, int n_in,
                              void* d_out, int out_size, void* d_ws, size_t ws_size,
                              hipStream_t stream) {
    const float* x = (const float*)d_in[0];
    const int* ei = (const int*)d_in[1];
    // d_in[2] = batch (unused, single graph)
    const float* W1a = (const float*)d_in[3];
    const float* b1a = (const float*)d_in[4];
    const float* W1b = (const float*)d_in[5];
    const float* b1b = (const float*)d_in[6];
    const float* gamma1 = (const float*)d_in[7];
    const float* beta1 = (const float*)d_in[8];
    const float* W2a = (const float*)d_in[9];
    const float* b2a = (const float*)d_in[10];
    const float* W2b = (const float*)d_in[11];
    const float* b2b = (const float*)d_in[12];
    const float* gamma2 = (const float*)d_in[13];
    const float* beta2 = (const float*)d_in[14];

    const int N = in_sizes[0] / 64;
    const int E = in_sizes[1] / 2;
    const int NC = N * 64;

    char* ws = (char*)d_ws;
    size_t off = 0;
    auto alloc = [&](size_t bytes) {
        char* p = ws + off;
        off += (bytes + 255) & ~(size_t)255;
        return p;
    };
    float* acc = (float*)alloc((size_t)NC * 4);                   // layer-1 pre-BN output
    unsigned short* xb = (unsigned short*)alloc((size_t)NC * 2);  // bf16 feature table
    unsigned short* pw = (unsigned short*)alloc(24576 * 2);
    float* stats = (float*)alloc(256 * 4);
    int* count = (int*)alloc((size_t)N * 4);
    int* offsets = (int*)alloc((size_t)(N + 1) * 4);
    int* cursor = (int*)alloc((size_t)(N + 1) * 4);
    int* ssrc = (int*)alloc((size_t)E * 4);
    int* bsums = (int*)alloc(1024 * 4);

    const int* esrc = ei;
    const int* edst = ei + E;

    // pack weights + zero stats/count
    int pgrid = (24832 + N + 255) / 256;
    pack_all<<<pgrid, 256, 0, stream>>>(W1a, W1b, W2a, W2b, pw, stats, count, N);

    // bf16 table + dst histogram
    int n4 = NC / 4;
    int big = max(n4, E);
    cvt_hist<<<(big + 255) / 256, 256, 0, stream>>>(x, xb, n4, edst, count, E);

    // two-level scan (counting sort offsets)
    int nb = (N + 1023) / 1024;
    scan1<<<nb, 256, 0, stream>>>(count, offsets, bsums, N);
    scan2<<<1, 256, 0, stream>>>(bsums, offsets, N, nb);
    scan3<<<(N + 255) / 256, 256, 0, stream>>>(offsets, cursor, bsums, N);
    scatter_kernel<<<(E + 255) / 256, 256, 0, stream>>>(esrc, edst, cursor, ssrc, E);

    int cgrid = (n4 + 255) / 256;
    int egrid = (N + 7) / 8;  // 4 waves/block, 2 nodes/wave

    // layer 1
    edgeconv_sorted<<<egrid, 256, 0, stream>>>(xb, ssrc, offsets, pw, pw + 4096, pw + 8192,
                                               b1a, b1b, acc, N);
    bn_stats<<<512, 256, 0, stream>>>(acc, stats, N);
    bn_apply<<<cgrid, 256, 0, stream>>>(acc, stats, gamma1, beta1, xb, nullptr, n4, 1.0f / N);

    // layer 2
    edgeconv_sorted<<<egrid, 256, 0, stream>>>(xb, ssrc, offsets, pw + 12288, pw + 16384,
                                               pw + 20480, b2a, b2b, (float*)d_out, N);
    bn_stats<<<512, 256, 0, stream>>>((float*)d_out, stats + 128, N);
    bn_apply<<<cgrid, 256, 0, stream>>>((float*)d_out, stats + 128, gamma2, beta2, nullptr,
                                        (float*)d_out, n4, 1.0f / N);
}

// Round 8
// 267.632 us; speedup vs baseline: 1.4908x; 1.1101x over previous
//
#include <hip/hip_runtime.h>
#include <hip/hip_bf16.h>

typedef float f32x4 __attribute__((ext_vector_type(4)));
typedef short s16x8 __attribute__((ext_vector_type(8)));

#define EPS 1e-5f

__device__ __forceinline__ unsigned short f32_to_bf16_rne(float f) {
    unsigned u = __float_as_uint(f);
    unsigned r = u + 0x7FFFu + ((u >> 16) & 1u);
    return (unsigned short)(r >> 16);
}

// packed 2x bf16 via HW converter (RNE): lo = a, hi = b
__device__ __forceinline__ unsigned cvtpk(float a, float b) {
    unsigned d;
    asm("v_cvt_pk_bf16_f32 %0, %1, %2" : "=v"(d) : "v"(a), "v"(b));
    return d;
}

// DPP helper (compile-time ctrl), all lanes active
#define DPPF(v, c) __int_as_float(__builtin_amdgcn_update_dpp(0, __float_as_int(v), (c), 0xF, 0xF, true))
// ds_swizzle xor4 (BitMode: and=0x1F, or=0, xor=4)
#define SWZ4(v) __int_as_float(__builtin_amdgcn_ds_swizzle(__float_as_int(v), 0x101F))

// ---------------- weight packing + buffer zeroing ----------------
// 6 matrices, each 64x64 packed as [2][4][64][8] bf16 (4096 ushorts):
//  m=0: W1xi = W1a[0:64]-W1a[64:128]   m=1: W1xj = W1a[64:128]   m=2: W1b
//  m=3: W2xi = W2a[0:64]-W2a[64:128]   m=4: W2xj = W2a[64:128]   m=5: W2b
__global__ void pack_all(const float* __restrict__ W1a, const float* __restrict__ W1b,
                         const float* __restrict__ W2a, const float* __restrict__ W2b,
                         unsigned short* __restrict__ p, float* __restrict__ stats,
                         int* __restrict__ count, int N) {
    int idx = blockIdx.x * 256 + threadIdx.x;
    if (idx < 24576) {
        int m = idx >> 12;
        int t = idx & 4095;
        int j = t & 7;
        int lane = (t >> 3) & 63;
        int mt = (t >> 9) & 3;
        int kc = t >> 11;
        int k = kc * 32 + (lane >> 4) * 8 + j;
        int c = mt * 16 + (lane & 15);
        float v;
        switch (m) {
            case 0: v = W1a[k * 64 + c] - W1a[(k + 64) * 64 + c]; break;
            case 1: v = W1a[(k + 64) * 64 + c]; break;
            case 2: v = W1b[k * 64 + c]; break;
            case 3: v = W2a[k * 64 + c] - W2a[(k + 64) * 64 + c]; break;
            case 4: v = W2a[(k + 64) * 64 + c]; break;
            default: v = W2b[k * 64 + c]; break;
        }
        p[idx] = f32_to_bf16_rne(v);
    } else if (idx < 24832) {
        stats[idx - 24576] = 0.f;
    } else if (idx - 24832 < N) {
        count[idx - 24832] = 0;
    }
}

// ---------------- f32 -> bf16 table convert + dst histogram ----------------
__global__ void cvt_hist(const float* __restrict__ in, unsigned short* __restrict__ out, int n4,
                         const int* __restrict__ edst, int* __restrict__ count, int E) {
    int i = blockIdx.x * 256 + threadIdx.x;
    if (i < n4) {
        f32x4 v = ((const f32x4*)in)[i];
        uint2 pr;
        pr.x = cvtpk(v[0], v[1]);
        pr.y = cvtpk(v[2], v[3]);
        *(uint2*)(out + i * 4) = pr;
    }
    if (i < E) atomicAdd(&count[edst[i]], 1);
}

// ---------------- two-level scan: 1024 elems/block ----------------
__global__ void scan1(const int* __restrict__ count, int* __restrict__ offsets,
                      int* __restrict__ bsums, int N) {
    __shared__ int sdata[256];
    int t = threadIdx.x;
    int base = blockIdx.x * 1024 + t * 4;
    int4 v = {0, 0, 0, 0};
    if (base + 3 < N) {
        v = *(const int4*)(count + base);
    } else {
        if (base + 0 < N) v.x = count[base + 0];
        if (base + 1 < N) v.y = count[base + 1];
        if (base + 2 < N) v.z = count[base + 2];
    }
    int s = v.x + v.y + v.z + v.w;
    sdata[t] = s;
    __syncthreads();
    for (int off = 1; off < 256; off <<= 1) {
        int u = (t >= off) ? sdata[t - off] : 0;
        __syncthreads();
        sdata[t] += u;
        __syncthreads();
    }
    int excl = sdata[t] - s;
    if (t == 255) bsums[blockIdx.x] = sdata[255];
    int o0 = excl;
    int o1 = o0 + v.x;
    int o2 = o1 + v.y;
    int o3 = o2 + v.z;
    if (base + 0 < N) offsets[base + 0] = o0;
    if (base + 1 < N) offsets[base + 1] = o1;
    if (base + 2 < N) offsets[base + 2] = o2;
    if (base + 3 < N) offsets[base + 3] = o3;
}

__global__ void scan2(int* __restrict__ bsums, int* __restrict__ offsets, int N, int nb) {
    __shared__ int sdata[256];
    int t = threadIdx.x;
    int s = (t < nb) ? bsums[t] : 0;
    sdata[t] = s;
    __syncthreads();
    for (int off = 1; off < 256; off <<= 1) {
        int u = (t >= off) ? sdata[t - off] : 0;
        __syncthreads();
        sdata[t] += u;
        __syncthreads();
    }
    if (t < nb) bsums[t] = sdata[t] - s;
    if (t == 255) offsets[N] = sdata[255];
}

__global__ void scan3(int* __restrict__ offsets, int* __restrict__ cursor,
                      const int* __restrict__ bsums, int N) {
    int i = blockIdx.x * 256 + threadIdx.x;
    if (i < N) {
        int v = offsets[i] + bsums[i >> 10];
        offsets[i] = v;
        cursor[i] = v;
    }
}

__global__ void scatter_kernel(const int* __restrict__ esrc, const int* __restrict__ edst,
                               int* __restrict__ cursor, int* __restrict__ ssrc, int E) {
    int i = blockIdx.x * 256 + threadIdx.x;
    if (i < E) {
        int d = edst[i];
        int pos = atomicAdd(&cursor[d], 1);
        ssrc[pos] = esrc[i];
    }
}

// ---------------- fused EdgeConv on dst-sorted edges ----------------
// h = relu(xi@Wxi + xj@Wxj + b); C-init = bias + xi-part (once per node).
// Epilogue: 4-step reduce-scatter across the 16 columns -> 1 channel/lane,
// fused BN stats (per-lane register accumulation + block LDS reduce + atomics).
#define LSTR 88  // LDS row stride in ushorts
__global__ __launch_bounds__(256, 3) void edgeconv_sorted(
    const unsigned short* __restrict__ xb,    // [N][64] bf16 features
    const int* __restrict__ ssrc,             // [E] src idx sorted by dst
    const int* __restrict__ offsets,          // [N+1]
    const unsigned short* __restrict__ pWxi,  // packed [2][4][64][8]
    const unsigned short* __restrict__ pWxj,
    const unsigned short* __restrict__ pWb,
    const float* __restrict__ ba,
    const float* __restrict__ bb,
    float* __restrict__ out,                  // [N][64] f32 (fully written)
    float* __restrict__ statsOut,             // [128] sum/sumsq accumulators
    int N) {
    __shared__ __align__(16) unsigned short xh[4][16 * LSTR];  // xstage/h1 aliased
    __shared__ float sred[128];
    const int tid = threadIdx.x;
    const int w = tid >> 6;
    const int lane = tid & 63;
    const int g = lane >> 4;
    const int r = lane & 15;
    const int srow = lane >> 2;  // staging: row slot this lane serves
    const int schk = lane & 3;   // staging: 16B chunk within row half

    if (tid < 128) sred[tid] = 0.f;
    __syncthreads();

    // persistent weight fragments: xj-part of layer1 + layer2
    s16x8 axj[2][4], ab[2][4];
#pragma unroll
    for (int kc = 0; kc < 2; ++kc)
#pragma unroll
        for (int mt = 0; mt < 4; ++mt) {
            axj[kc][mt] = *(const s16x8*)(pWxj + ((kc * 4 + mt) * 64 + lane) * 8);
            ab[kc][mt] = *(const s16x8*)(pWb + ((kc * 4 + mt) * 64 + lane) * 8);
        }

    unsigned short* myb = xh[w];
    const int totalWaves = gridDim.x * 4;
    const f32x4 zf = {0.f, 0.f, 0.f, 0.f};

    const int ch = (r >> 2) * 16 + g * 4 + (r & 3);  // this lane's output channel
    const float b2l = bb[ch];
    float bsum = 0.f, bss = 0.f;

    for (int node = blockIdx.x * 4 + w; node < N; node += totalWaves) {
        const int segB = offsets[node];
        const int segE = offsets[node + 1];

        f32x4 rm[4];
#pragma unroll
        for (int mt = 0; mt < 4; ++mt)
            rm[mt] = (f32x4){-INFINITY, -INFINITY, -INFINITY, -INFINITY};

        if (segB < segE) {
            // first tile prefetch (ssrc + rows) before accxi MFMA work
            int sv = ssrc[min(segB + srow, segE - 1)];
            s16x8 ra = *(const s16x8*)(xb + sv * 64 + schk * 8);
            s16x8 rb = *(const s16x8*)(xb + sv * 64 + 32 + schk * 8);

            // xi-part + bias, once per node (broadcast across the 16 columns)
            s16x8 xi1 = *(const s16x8*)(xb + node * 64 + g * 8);
            s16x8 xi2 = *(const s16x8*)(xb + node * 64 + 32 + g * 8);
            f32x4 accxi[4];
#pragma unroll
            for (int mt = 0; mt < 4; ++mt)
                accxi[mt] = *(const f32x4*)(ba + mt * 16 + g * 4);
#pragma unroll
            for (int mt = 0; mt < 4; ++mt) {
                s16x8 f0 = *(const s16x8*)(pWxi + ((0 * 4 + mt) * 64 + lane) * 8);
                accxi[mt] = __builtin_amdgcn_mfma_f32_16x16x32_bf16(f0, xi1, accxi[mt], 0, 0, 0);
                s16x8 f1 = *(const s16x8*)(pWxi + ((1 * 4 + mt) * 64 + lane) * 8);
                accxi[mt] = __builtin_amdgcn_mfma_f32_16x16x32_bf16(f1, xi2, accxi[mt], 0, 0, 0);
            }

            for (int t0 = segB; t0 < segE; t0 += 16) {
                // stage prefetched rows (per-wave LDS: in-order, no barrier)
                *(s16x8*)(myb + srow * LSTR + schk * 8) = ra;
                *(s16x8*)(myb + srow * LSTR + 32 + schk * 8) = rb;
                s16x8 xj1 = *(const s16x8*)(myb + r * LSTR + g * 8);
                s16x8 xj2 = *(const s16x8*)(myb + r * LSTR + 32 + g * 8);

                // prefetch next tile before the compute chain
                int t1 = t0 + 16;
                if (t1 < segE) {
                    int sv2 = ssrc[min(t1 + srow, segE - 1)];
                    ra = *(const s16x8*)(xb + sv2 * 64 + schk * 8);
                    rb = *(const s16x8*)(xb + sv2 * 64 + 32 + schk * 8);
                }

                // layer 1 (C-init = xi-part + bias)
                f32x4 acc[4];
#pragma unroll
                for (int mt = 0; mt < 4; ++mt) {
                    acc[mt] = __builtin_amdgcn_mfma_f32_16x16x32_bf16(axj[0][mt], xj1, accxi[mt], 0, 0, 0);
                    acc[mt] = __builtin_amdgcn_mfma_f32_16x16x32_bf16(axj[1][mt], xj2, acc[mt], 0, 0, 0);
                }

                // relu + HW bf16 pack, bounce through LDS (aliased buffer, in-order DS)
#pragma unroll
                for (int mt = 0; mt < 4; ++mt) {
                    uint2 pr;
                    pr.x = cvtpk(fmaxf(acc[mt][0], 0.f), fmaxf(acc[mt][1], 0.f));
                    pr.y = cvtpk(fmaxf(acc[mt][2], 0.f), fmaxf(acc[mt][3], 0.f));
                    *(uint2*)(myb + r * LSTR + mt * 16 + g * 4) = pr;
                }
                s16x8 p0 = *(const s16x8*)(myb + r * LSTR + g * 8);
                s16x8 p1 = *(const s16x8*)(myb + r * LSTR + 32 + g * 8);

                f32x4 acc2[4];
#pragma unroll
                for (int mt = 0; mt < 4; ++mt) {
                    acc2[mt] = __builtin_amdgcn_mfma_f32_16x16x32_bf16(ab[0][mt], p0, zf, 0, 0, 0);
                    acc2[mt] = __builtin_amdgcn_mfma_f32_16x16x32_bf16(ab[1][mt], p1, acc2[mt], 0, 0, 0);
                }

                // unconditional: clamped columns duplicate a real edge (idempotent for max)
#pragma unroll
                for (int mt = 0; mt < 4; ++mt)
#pragma unroll
                    for (int q = 0; q < 4; ++q)
                        rm[mt][q] = fmaxf(rm[mt][q], acc2[mt][q]);
            }
        }

        // ---- reduce-scatter: max over the 16 columns; lane r ends with value v=r ----
        float k8[8];
#pragma unroll
        for (int j = 0; j < 8; ++j) {
            float lo = rm[j >> 2][j & 3];        // value j
            float hv = rm[(j >> 2) + 2][j & 3];  // value j+8
            float tlo = DPPF(lo, 0x128);         // row_ror:8 == xor8 within 16-row
            float thi = DPPF(hv, 0x128);
            float own = (r & 8) ? hv : lo;
            float oth = (r & 8) ? thi : tlo;
            k8[j] = fmaxf(own, oth);
        }
        float k4[4];
#pragma unroll
        for (int j = 0; j < 4; ++j) {
            float ta = SWZ4(k8[j]);
            float tb = SWZ4(k8[j + 4]);
            float own = (r & 4) ? k8[j + 4] : k8[j];
            float oth = (r & 4) ? tb : ta;
            k4[j] = fmaxf(own, oth);
        }
        float k2[2];
#pragma unroll
        for (int j = 0; j < 2; ++j) {
            float ta = DPPF(k4[j], 0x4E);      // quad_perm [2,3,0,1] == xor2
            float tb = DPPF(k4[j + 2], 0x4E);
            float own = (r & 2) ? k4[j + 2] : k4[j];
            float oth = (r & 2) ? tb : ta;
            k2[j] = fmaxf(own, oth);
        }
        float ta = DPPF(k2[0], 0xB1);          // quad_perm [1,0,3,2] == xor1
        float tb = DPPF(k2[1], 0xB1);
        float vfin = fmaxf((r & 1) ? k2[1] : k2[0], (r & 1) ? tb : ta);

        float o = fmaxf(vfin + b2l, 0.f);      // bias2 + relu (post-max; -inf -> 0 fill)
        out[node * 64 + ch] = o;
        bsum += o;
        bss += o * o;
    }

    // ---- fused BN stats: block LDS reduce, then 128 global atomics ----
    atomicAdd(&sred[ch], bsum);
    atomicAdd(&sred[64 + ch], bss);
    __syncthreads();
    if (tid < 128) atomicAdd(&statsOut[tid], sred[tid]);
}

// ---------------- batchnorm apply (optionally emit bf16 table for next layer) ----------------
__global__ void bn_apply(const float* __restrict__ in, const float* __restrict__ stats,
                         const float* __restrict__ gamma, const float* __restrict__ beta,
                         unsigned short* __restrict__ outb, float* __restrict__ outf,
                         int n4, float invN) {
    int i = blockIdx.x * 256 + threadIdx.x;
    if (i >= n4) return;
    int c0 = (i * 4) & 63;
    f32x4 v = ((const f32x4*)in)[i];
    f32x4 o;
#pragma unroll
    for (int q = 0; q < 4; ++q) {
        int c = c0 + q;
        float mean = stats[c] * invN;
        float var = stats[64 + c] * invN - mean * mean;
        float sc = gamma[c] * rsqrtf(var + EPS);
        o[q] = (v[q] - mean) * sc + beta[c];
    }
    if (outb) {
        uint2 pr;
        pr.x = cvtpk(o[0], o[1]);
        pr.y = cvtpk(o[2], o[3]);
        *(uint2*)(outb + i * 4) = pr;
    } else {
        ((f32x4*)outf)[i] = o;
    }
}

extern "C" void kernel_launch(void* const* d_in, const int* in_sizes, int n_in,
                              void* d_out, int out_size, void* d_ws, size_t ws_size,
                              hipStream_t stream) {
    const float* x = (const float*)d_in[0];
    const int* ei = (const int*)d_in[1];
    // d_in[2] = batch (unused, single graph)
    const float* W1a = (const float*)d_in[3];
    const float* b1a = (const float*)d_in[4];
    const float* W1b = (const float*)d_in[5];
    const float* b1b = (const float*)d_in[6];
    const float* gamma1 = (const float*)d_in[7];
    const float* beta1 = (const float*)d_in[8];
    const float* W2a = (const float*)d_in[9];
    const float* b2a = (const float*)d_in[10];
    const float* W2b = (const float*)d_in[11];
    const float* b2b = (const float*)d_in[12];
    const float* gamma2 = (const float*)d_in[13];
    const float* beta2 = (const float*)d_in[14];

    const int N = in_sizes[0] / 64;
    const int E = in_sizes[1] / 2;
    const int NC = N * 64;

    char* ws = (char*)d_ws;
    size_t off = 0;
    auto alloc = [&](size_t bytes) {
        char* p = ws + off;
        off += (bytes + 255) & ~(size_t)255;
        return p;
    };
    float* acc = (float*)alloc((size_t)NC * 4);                   // layer-1 pre-BN output
    unsigned short* xb = (unsigned short*)alloc((size_t)NC * 2);  // bf16 feature table
    unsigned short* pw = (unsigned short*)alloc(24576 * 2);
    float* stats = (float*)alloc(256 * 4);
    int* count = (int*)alloc((size_t)N * 4);
    int* offsets = (int*)alloc((size_t)(N + 1) * 4);
    int* cursor = (int*)alloc((size_t)(N + 1) * 4);
    int* ssrc = (int*)alloc((size_t)E * 4);
    int* bsums = (int*)alloc(1024 * 4);

    const int* esrc = ei;
    const int* edst = ei + E;

    // pack weights + zero stats/count
    int pgrid = (24832 + N + 255) / 256;
    pack_all<<<pgrid, 256, 0, stream>>>(W1a, W1b, W2a, W2b, pw, stats, count, N);

    // bf16 table + dst histogram
    int n4 = NC / 4;
    int big = max(n4, E);
    cvt_hist<<<(big + 255) / 256, 256, 0, stream>>>(x, xb, n4, edst, count, E);

    // two-level scan (counting sort offsets)
    int nb = (N + 1023) / 1024;
    scan1<<<nb, 256, 0, stream>>>(count, offsets, bsums, N);
    scan2<<<1, 256, 0, stream>>>(bsums, offsets, N, nb);
    scan3<<<(N + 255) / 256, 256, 0, stream>>>(offsets, cursor, bsums, N);
    scatter_kernel<<<(E + 255) / 256, 256, 0, stream>>>(esrc, edst, cursor, ssrc, E);

    int cgrid = (n4 + 255) / 256;
    const int egrid = 2048;  // grid-stride; bounds per-address atomic chains

    // layer 1 (+fused stats)
    edgeconv_sorted<<<egrid, 256, 0, stream>>>(xb, ssrc, offsets, pw, pw + 4096, pw + 8192,
                                               b1a, b1b, acc, stats, N);
    bn_apply<<<cgrid, 256, 0, stream>>>(acc, stats, gamma1, beta1, xb, nullptr, n4, 1.0f / N);

    // layer 2 (+fused stats)
    edgeconv_sorted<<<egrid, 256, 0, stream>>>(xb, ssrc, offsets, pw + 12288, pw + 16384,
                                               pw + 20480, b2a, b2b, (float*)d_out, stats + 128, N);
    bn_apply<<<cgrid, 256, 0, stream>>>((float*)d_out, stats + 128, gamma2, beta2, nullptr,
                                        (float*)d_out, n4, 1.0f / N);
}